// Round 6
// baseline (232.853 us; speedup 1.0000x reference)
//
#include <hip/hip_runtime.h>
#include <cstdint>
#include <cstddef>

#define S_LEN   2048
#define N_HEADS 8
#define N_BATCH 2
#define TOPK    409      // int(2048 * (1.0 - 0.8)) in python double arithmetic
#define HALF_WIN 32
#define NT      256
#define PT      8        // S_LEN / NT
#define KEY_P0  0x80000000u   // mono(+0.0f)
#define KEY_N0  0x7FFFFFFFu   // mono(-0.0f)  (total order: -0 < +0)

__device__ __forceinline__ unsigned mono(float f) {
  unsigned u = __float_as_uint(f);
  return (u & 0x80000000u) ? ~u : (u | 0x80000000u);
}

__device__ __forceinline__ unsigned mbcnt64(unsigned long long m) {
  return __builtin_amdgcn_mbcnt_hi((unsigned)(m >> 32),
         __builtin_amdgcn_mbcnt_lo((unsigned)m, 0u));
}

// ------------------------- k_gmask (unchanged, at HBM roofline) -------------

struct SelScratch {
  unsigned hist[256];
  unsigned sbuf[256];
  unsigned bk[2];
};

__device__ __forceinline__ unsigned block_sum(unsigned c, SelScratch* s) {
  const int t = threadIdx.x;
  s->sbuf[t] = c;
  __syncthreads();
  #pragma unroll
  for (int d = 128; d > 0; d >>= 1) {
    if (t < d) s->sbuf[t] += s->sbuf[t + d];
    __syncthreads();
  }
  unsigned r = s->sbuf[0];
  __syncthreads();
  return r;
}

__device__ void radix_select(const unsigned* keys, int k, unsigned n0, unsigned n1,
                             SelScratch* s, unsigned* T_out, int* kk_out) {
  const int t = threadIdx.x;
  unsigned prefix = 0, done = 0;
  unsigned kk = (unsigned)k;
  #pragma unroll
  for (int shift = 24; shift >= 0; shift -= 8) {
    s->hist[t] = 0;
    __syncthreads();
    if (t == 0 && n0 != 0 && (KEY_P0 & done) == prefix)
      atomicAdd(&s->hist[(KEY_P0 >> shift) & 255u], n0);
    if (t == 1 && n1 != 0 && (KEY_N0 & done) == prefix)
      atomicAdd(&s->hist[(KEY_N0 >> shift) & 255u], n1);
    #pragma unroll
    for (int q = 0; q < PT; ++q) {
      unsigned kj = keys[t + NT * q];
      if (kj != KEY_P0 && kj != KEY_N0 && (kj & done) == prefix)
        atomicAdd(&s->hist[(kj >> shift) & 255u], 1u);
    }
    __syncthreads();
    s->sbuf[t] = s->hist[t];
    __syncthreads();
    for (int d = 1; d < 256; d <<= 1) {
      unsigned a = (t + d < 256) ? s->sbuf[t + d] : 0u;
      __syncthreads();
      s->sbuf[t] += a;
      __syncthreads();
    }
    unsigned suf_ge = s->sbuf[t];
    unsigned suf_gt = (t < 255) ? s->sbuf[t + 1] : 0u;
    if (suf_gt < kk && kk <= suf_ge) {
      s->bk[0] = (unsigned)t;
      s->bk[1] = kk - suf_gt;
    }
    __syncthreads();
    prefix |= s->bk[0] << shift;
    kk = s->bk[1];
    done |= 0xFFu << shift;
    __syncthreads();
  }
  *T_out = prefix;
  *kk_out = (int)kk;
}

__device__ __forceinline__ int stable_rank_base(int c, SelScratch* s) {
  const int t = threadIdx.x;
  s->sbuf[t] = (unsigned)c;
  __syncthreads();
  for (int d = 1; d < 256; d <<= 1) {
    unsigned a = (t >= d) ? s->sbuf[t - d] : 0u;
    __syncthreads();
    s->sbuf[t] += a;
    __syncthreads();
  }
  int base = (t == 0) ? 0 : (int)s->sbuf[t - 1];
  __syncthreads();
  return base;
}

__global__ __launch_bounds__(NT) void k_gmask(const float* __restrict__ scores,
                                              unsigned* __restrict__ gwords) {
  __shared__ __align__(16) unsigned keys[S_LEN];
  __shared__ SelScratch scr;
  __shared__ __align__(4) unsigned char gb[NT];
  const int t = threadIdx.x;
  const int blk = blockIdx.x;          // b * S + i
  const int b = blk >> 11;
  const int i = blk & 2047;
  const size_t base = (((size_t)b * N_HEADS) * S_LEN + i) * S_LEN;

  unsigned c0 = 0, c1 = 0;
  #pragma unroll
  for (int s4 = 0; s4 < 2; ++s4) {
    const int j0 = (t + NT * s4) * 4;
    float4 a = *(const float4*)(scores + base + j0);
    #pragma unroll
    for (int h = 1; h < N_HEADS; ++h) {
      float4 x = *(const float4*)(scores + base + (size_t)h * S_LEN * S_LEN + j0);
      a.x += x.x; a.y += x.y; a.z += x.z; a.w += x.w;   // sequential h order
    }
    unsigned kqa[4] __attribute__((aligned(16)));
    kqa[0] = mono(a.x); kqa[1] = mono(a.y); kqa[2] = mono(a.z); kqa[3] = mono(a.w);
    #pragma unroll
    for (int q = 0; q < 4; ++q) {
      c0 += (kqa[q] == KEY_P0);
      c1 += (kqa[q] == KEY_N0);
    }
    *(uint4*)(&keys[j0]) = *(uint4*)kqa;
  }
  __syncthreads();

  unsigned ns = block_sum(c0 | (c1 << 16), &scr);
  unsigned T; int kk;
  radix_select(keys, TOPK, ns & 0xFFFFu, ns >> 16, &scr, &T, &kk);

  int c = 0;
  #pragma unroll
  for (int e = 0; e < PT; ++e) c += (keys[t * PT + e] == T);
  int r = stable_rank_base(c, &scr);

  unsigned byte = 0;
  #pragma unroll
  for (int e = 0; e < PT; ++e) {
    unsigned kj = keys[t * PT + e];
    bool sel;
    if (kj > T)       sel = true;
    else if (kj == T) { sel = (r < kk); ++r; }
    else              sel = false;
    byte |= (unsigned)sel << e;
  }
  gb[t] = (unsigned char)byte;
  __syncthreads();
  if (t < 64) gwords[(size_t)blk * 64 + t] = ((const unsigned*)gb)[t];
}

// ---------------- k_final: 4 waves/block, one wave per (b,h,i) row ----------
// Wave-private LDS slices, zero barriers (LDS is in-order within a wave;
// __threadfence_block() fences compiler reordering around the atomics).
// Analytic zero-branch: order is positives > +0 > -0 > negatives, so with
// np/n0/n1 known the threshold is resolved without any histogram whenever
// np < k <= np+n0 (~50% of rows). Otherwise radix-select restricted to the
// positive (or, pathologically, negative) keys only.

__device__ __forceinline__ void radix_range(const unsigned (&keys)[32], unsigned kk0,
                                            bool pos, unsigned* h, int l,
                                            unsigned& T_ret, unsigned& kk_ret) {
  unsigned prefix = 0, done = 0, kk = kk0;
  unsigned T = 0;
  bool resolved = false;
  #pragma unroll
  for (int pass = 0; pass < 4; ++pass) {
    const int shift = 24 - 8 * pass;
    *(uint4*)&h[l * 4] = make_uint4(0, 0, 0, 0);
    __threadfence_block();
    #pragma unroll
    for (int q = 0; q < 32; ++q) {
      unsigned kj = keys[q];
      bool in = pos ? (kj > KEY_P0) : (kj < KEY_N0);
      if (in && (kj & done) == prefix)
        atomicAdd(&h[(kj >> shift) & 255u], 1u);
    }
    __threadfence_block();
    // Suffix-sum over 256 bins: 4 bins/lane local suffix + wave suffix scan.
    uint4 hv = *(const uint4*)&h[l * 4];
    unsigned s3 = hv.w;
    unsigned s2 = hv.z + s3;
    unsigned s1 = hv.y + s2;
    unsigned s0 = hv.x + s1;
    unsigned inc = s0;                       // inclusive over lanes >= l
    #pragma unroll
    for (int d = 1; d < 64; d <<= 1) {
      unsigned o = __shfl_down(inc, d);
      inc += (l + d < 64) ? o : 0u;
    }
    const unsigned tail = inc - s0;          // sum over lanes > l
    const unsigned ge[4] = {s0 + tail, s1 + tail, s2 + tail, s3 + tail};
    const unsigned gt[4] = {s1 + tail, s2 + tail, s3 + tail, tail};
    unsigned packed = 0;
    bool found = false;
    #pragma unroll
    for (int q = 0; q < 4; ++q) {
      if (gt[q] < kk && kk <= ge[q]) {       // exactly one (lane,q) in wave
        // digit(8) | bucket_count(12) | kk_residual(12)
        packed = ((unsigned)(4 * l + q) << 24) | ((ge[q] - gt[q]) << 12) | (kk - gt[q]);
        found = true;
      }
    }
    unsigned long long bal = __ballot(found);
    int srcl = __ffsll((long long)bal) - 1;
    packed = __shfl(packed, srcl);
    const unsigned cnt = (packed >> 12) & 0xFFFu;
    kk = packed & 0xFFFu;
    prefix |= (packed >> 24) << shift;
    done |= 0xFFu << shift;
    // Early exit: single surviving key -> find in registers, OR-broadcast.
    if (cnt == 1u) {
      unsigned cand = 0;
      #pragma unroll
      for (int q = 0; q < 32; ++q) {
        unsigned kj = keys[q];
        bool in = pos ? (kj > KEY_P0) : (kj < KEY_N0);
        if (in && (kj & done) == prefix) cand = kj;
      }
      #pragma unroll
      for (int d = 1; d < 64; d <<= 1) cand |= __shfl_xor(cand, d);
      T = cand;
      resolved = true;
      break;
    }
  }
  if (!resolved) T = prefix;
  T_ret = T;
  kk_ret = kk;
}

__global__ __launch_bounds__(256) void k_final(const float* __restrict__ scores,
                                               const float* __restrict__ randu,
                                               const unsigned* __restrict__ gwords,
                                               float* __restrict__ out) {
  __shared__ __align__(16) unsigned hist[4][256];
  __shared__ unsigned gm[4][64];
  const int l = threadIdx.x & 63;          // lane
  const int w = threadIdx.x >> 6;          // wave in block
  const int row = blockIdx.x * 4 + w;      // (b*8 + h)*2048 + i
  const int i = row & 2047;
  const int b = row >> 14;
  const size_t base = (size_t)row * S_LEN;
  const float thr = (float)(1.0 - 0.8);    // 0x3E4CCCCD, JAX f32 demotion
  unsigned* h = hist[w];
  unsigned* g = gm[w];

  g[l] = gwords[((size_t)(b << 11) + i) * 64 + l];
  // no barrier: wave-private slice, LDS in-order within the wave

  // Build 32 keys/lane: lane l owns j = 256*s + 4*l + e  (s=0..7, e=0..3).
  unsigned keys[32];
  unsigned c0 = 0, c1 = 0, cp = 0;
  #pragma unroll
  for (int s = 0; s < 8; ++s) {
    const int j0 = 256 * s + 4 * l;
    float4 sc = *(const float4*)(scores + base + j0);
    float4 ru = *(const float4*)(randu + base + j0);
    const unsigned gmw = g[8 * s + (l >> 3)];
    const float scv[4] = {sc.x, sc.y, sc.z, sc.w};
    const float ruv[4] = {ru.x, ru.y, ru.z, ru.w};
    #pragma unroll
    for (int e = 0; e < 4; ++e) {
      const int j = j0 + e;
      bool loc = (j >= i - HALF_WIN) && (j < i + HALF_WIN);
      bool gbit = (gmw >> (4 * (l & 7) + e)) & 1u;
      bool rnd = ruv[e] < thr;
      unsigned u = __float_as_uint(scv[e]);
      unsigned key;
      if (loc || gbit || rnd) key = (u & 0x80000000u) ? ~u : (u | 0x80000000u);
      else                    key = (u >> 31) ? KEY_N0 : KEY_P0;  // mono(+-0)
      c0 += (key == KEY_P0);
      c1 += (key == KEY_N0);
      cp += (key > KEY_P0);
      keys[4 * s + e] = key;
    }
  }

  // Wave butterfly reduce: n0 (+0 ties), n1 (-0 ties), np (kept positives).
  unsigned cs = c0 | (c1 << 16);
  #pragma unroll
  for (int d = 1; d < 64; d <<= 1) {
    cs += __shfl_xor(cs, d);
    cp += __shfl_xor(cp, d);
  }
  const unsigned n0 = cs & 0xFFFFu, n1 = cs >> 16, np = cp;

  // Resolve threshold T and tie-take count kk (wave-uniform branches).
  unsigned T, kk;
  if (TOPK <= np) {
    radix_range(keys, TOPK, true, h, l, T, kk);           // among positives
  } else if (TOPK <= np + n0) {
    T = KEY_P0; kk = TOPK - np;                           // ~50% of rows
  } else if (TOPK <= np + n0 + n1) {
    T = KEY_N0; kk = TOPK - np - n0;
  } else {
    radix_range(keys, TOPK - np - n0 - n1, false, h, l, T, kk);  // negatives
  }

  // Stable-rank selection + coalesced write.
  unsigned S_before = 0;                     // ties in j-blocks s' < s
  #pragma unroll
  for (int s = 0; s < 8; ++s) {
    unsigned long long bal[4];
    unsigned mb[4], own[4];
    #pragma unroll
    for (int e = 0; e < 4; ++e) {
      bal[e] = __ballot(keys[4 * s + e] == T);
      mb[e]  = mbcnt64(bal[e]);
      own[e] = (unsigned)((bal[e] >> l) & 1ull);
    }
    const unsigned cross = S_before + mb[0] + mb[1] + mb[2] + mb[3];
    float v[4] __attribute__((aligned(16)));
    unsigned run = 0;
    #pragma unroll
    for (int e = 0; e < 4; ++e) {
      unsigned kj = keys[4 * s + e];
      bool sel = (kj > T) || (kj == T && (cross + run) < kk);
      run += own[e];
      v[e] = sel ? 1.0f : 0.0f;
    }
    *(float4*)(out + base + 256 * s + 4 * l) = *(const float4*)v;
    S_before += (unsigned)(__popcll(bal[0]) + __popcll(bal[1]) +
                           __popcll(bal[2]) + __popcll(bal[3]));
  }
}

extern "C" void kernel_launch(void* const* d_in, const int* in_sizes, int n_in,
                              void* d_out, int out_size, void* d_ws, size_t ws_size,
                              hipStream_t stream) {
  const float* scores = (const float*)d_in[0];
  const float* randu  = (const float*)d_in[1];
  float* out = (float*)d_out;
  unsigned* gwords = (unsigned*)d_ws;  // needs N_BATCH*S_LEN*256 B = 1 MiB
  k_gmask<<<N_BATCH * S_LEN, NT, 0, stream>>>(scores, gwords);
  k_final<<<N_BATCH * N_HEADS * S_LEN / 4, 256, 0, stream>>>(scores, randu, gwords, out);
}

// Round 7
// 224.478 us; speedup vs baseline: 1.0373x; 1.0373x over previous
//
#include <hip/hip_runtime.h>
#include <cstdint>
#include <cstddef>

#define S_LEN   2048
#define N_HEADS 8
#define N_BATCH 2
#define TOPK    409      // int(2048 * (1.0 - 0.8)) in python double arithmetic
#define HALF_WIN 32
#define NT      256
#define PT      8        // S_LEN / NT
#define KEY_P0  0x80000000u   // mono(+0.0f)
#define KEY_N0  0x7FFFFFFFu   // mono(-0.0f)  (total order: -0 < +0)

__device__ __forceinline__ unsigned mono(float f) {
  unsigned u = __float_as_uint(f);
  return (u & 0x80000000u) ? ~u : (u | 0x80000000u);
}

__device__ __forceinline__ unsigned mbcnt64(unsigned long long m) {
  return __builtin_amdgcn_mbcnt_hi((unsigned)(m >> 32),
         __builtin_amdgcn_mbcnt_lo((unsigned)m, 0u));
}

// ------------------------- k_gmask (at HBM roofline) ------------------------
// NEW: ORs the (head-independent) local-window bits into gwords, so k_final
// doesn't have to compute the window per element.

struct SelScratch {
  unsigned hist[256];
  unsigned sbuf[256];
  unsigned bk[2];
};

__device__ __forceinline__ unsigned block_sum(unsigned c, SelScratch* s) {
  const int t = threadIdx.x;
  s->sbuf[t] = c;
  __syncthreads();
  #pragma unroll
  for (int d = 128; d > 0; d >>= 1) {
    if (t < d) s->sbuf[t] += s->sbuf[t + d];
    __syncthreads();
  }
  unsigned r = s->sbuf[0];
  __syncthreads();
  return r;
}

__device__ void radix_select(const unsigned* keys, int k, unsigned n0, unsigned n1,
                             SelScratch* s, unsigned* T_out, int* kk_out) {
  const int t = threadIdx.x;
  unsigned prefix = 0, done = 0;
  unsigned kk = (unsigned)k;
  #pragma unroll
  for (int shift = 24; shift >= 0; shift -= 8) {
    s->hist[t] = 0;
    __syncthreads();
    if (t == 0 && n0 != 0 && (KEY_P0 & done) == prefix)
      atomicAdd(&s->hist[(KEY_P0 >> shift) & 255u], n0);
    if (t == 1 && n1 != 0 && (KEY_N0 & done) == prefix)
      atomicAdd(&s->hist[(KEY_N0 >> shift) & 255u], n1);
    #pragma unroll
    for (int q = 0; q < PT; ++q) {
      unsigned kj = keys[t + NT * q];
      if (kj != KEY_P0 && kj != KEY_N0 && (kj & done) == prefix)
        atomicAdd(&s->hist[(kj >> shift) & 255u], 1u);
    }
    __syncthreads();
    s->sbuf[t] = s->hist[t];
    __syncthreads();
    for (int d = 1; d < 256; d <<= 1) {
      unsigned a = (t + d < 256) ? s->sbuf[t + d] : 0u;
      __syncthreads();
      s->sbuf[t] += a;
      __syncthreads();
    }
    unsigned suf_ge = s->sbuf[t];
    unsigned suf_gt = (t < 255) ? s->sbuf[t + 1] : 0u;
    if (suf_gt < kk && kk <= suf_ge) {
      s->bk[0] = (unsigned)t;
      s->bk[1] = kk - suf_gt;
    }
    __syncthreads();
    prefix |= s->bk[0] << shift;
    kk = s->bk[1];
    done |= 0xFFu << shift;
    __syncthreads();
  }
  *T_out = prefix;
  *kk_out = (int)kk;
}

__device__ __forceinline__ int stable_rank_base(int c, SelScratch* s) {
  const int t = threadIdx.x;
  s->sbuf[t] = (unsigned)c;
  __syncthreads();
  for (int d = 1; d < 256; d <<= 1) {
    unsigned a = (t >= d) ? s->sbuf[t - d] : 0u;
    __syncthreads();
    s->sbuf[t] += a;
    __syncthreads();
  }
  int base = (t == 0) ? 0 : (int)s->sbuf[t - 1];
  __syncthreads();
  return base;
}

__global__ __launch_bounds__(NT) void k_gmask(const float* __restrict__ scores,
                                              unsigned* __restrict__ gwords) {
  __shared__ __align__(16) unsigned keys[S_LEN];
  __shared__ SelScratch scr;
  __shared__ __align__(4) unsigned char gb[NT];
  const int t = threadIdx.x;
  const int blk = blockIdx.x;          // b * S + i
  const int b = blk >> 11;
  const int i = blk & 2047;
  const size_t base = (((size_t)b * N_HEADS) * S_LEN + i) * S_LEN;

  unsigned c0 = 0, c1 = 0;
  #pragma unroll
  for (int s4 = 0; s4 < 2; ++s4) {
    const int j0 = (t + NT * s4) * 4;
    float4 a = *(const float4*)(scores + base + j0);
    #pragma unroll
    for (int h = 1; h < N_HEADS; ++h) {
      float4 x = *(const float4*)(scores + base + (size_t)h * S_LEN * S_LEN + j0);
      a.x += x.x; a.y += x.y; a.z += x.z; a.w += x.w;   // sequential h order
    }
    unsigned kqa[4] __attribute__((aligned(16)));
    kqa[0] = mono(a.x); kqa[1] = mono(a.y); kqa[2] = mono(a.z); kqa[3] = mono(a.w);
    #pragma unroll
    for (int q = 0; q < 4; ++q) {
      c0 += (kqa[q] == KEY_P0);
      c1 += (kqa[q] == KEY_N0);
    }
    *(uint4*)(&keys[j0]) = *(uint4*)kqa;
  }
  __syncthreads();

  unsigned ns = block_sum(c0 | (c1 << 16), &scr);
  unsigned T; int kk;
  radix_select(keys, TOPK, ns & 0xFFFFu, ns >> 16, &scr, &T, &kk);

  int c = 0;
  #pragma unroll
  for (int e = 0; e < PT; ++e) c += (keys[t * PT + e] == T);
  int r = stable_rank_base(c, &scr);

  unsigned byte = 0;
  #pragma unroll
  for (int e = 0; e < PT; ++e) {
    unsigned kj = keys[t * PT + e];
    bool sel;
    if (kj > T)       sel = true;
    else if (kj == T) { sel = (r < kk); ++r; }
    else              sel = false;
    byte |= (unsigned)sel << e;
  }
  gb[t] = (unsigned char)byte;
  __syncthreads();
  if (t < 64) {
    unsigned wv = ((const unsigned*)gb)[t];
    // OR in local-window bits for word t (covers j in [32t, 32t+32)):
    int s0 = i - HALF_WIN - 32 * t;          // window [i-32, i+32) relative
    int e0 = i + HALF_WIN - 32 * t;
    s0 = s0 < 0 ? 0 : (s0 > 32 ? 32 : s0);
    e0 = e0 < 0 ? 0 : (e0 > 32 ? 32 : e0);
    unsigned lm = 0;
    if (e0 > s0) {
      unsigned hiM = (e0 == 32) ? 0xFFFFFFFFu : ((1u << e0) - 1u);
      lm = hiM & ~((1u << s0) - 1u);         // s0 < 32 here since e0 > s0
    }
    gwords[(size_t)blk * 64 + t] = wv | lm;
  }
}

// ---------------- k_final: 4 waves/block, one wave per (b,h,i) row ----------
// VALU-trimmed: branchless mono; counts via ballot + SALU popcount (no
// butterflies); selection uses wave-uniform 3-way branch per 256-col block
// (only the tie-boundary block runs the fine rank machinery). gwords already
// contain local|g.

__device__ __forceinline__ void radix_range(const unsigned (&keys)[32], unsigned kk0,
                                            bool pos, unsigned* h, int l,
                                            unsigned& T_ret, unsigned& kk_ret) {
  unsigned prefix = 0, done = 0, kk = kk0;
  unsigned T = 0;
  bool resolved = false;
  #pragma unroll
  for (int pass = 0; pass < 4; ++pass) {
    const int shift = 24 - 8 * pass;
    *(uint4*)&h[l * 4] = make_uint4(0, 0, 0, 0);
    __threadfence_block();
    #pragma unroll
    for (int q = 0; q < 32; ++q) {
      unsigned kj = keys[q];
      bool in = pos ? (kj > KEY_P0) : (kj < KEY_N0);
      if (in && (kj & done) == prefix)
        atomicAdd(&h[(kj >> shift) & 255u], 1u);
    }
    __threadfence_block();
    uint4 hv = *(const uint4*)&h[l * 4];
    unsigned s3 = hv.w;
    unsigned s2 = hv.z + s3;
    unsigned s1 = hv.y + s2;
    unsigned s0 = hv.x + s1;
    unsigned inc = s0;
    #pragma unroll
    for (int d = 1; d < 64; d <<= 1) {
      unsigned o = __shfl_down(inc, d);
      inc += (l + d < 64) ? o : 0u;
    }
    const unsigned tail = inc - s0;
    const unsigned ge[4] = {s0 + tail, s1 + tail, s2 + tail, s3 + tail};
    const unsigned gt[4] = {s1 + tail, s2 + tail, s3 + tail, tail};
    unsigned packed = 0;
    bool found = false;
    #pragma unroll
    for (int q = 0; q < 4; ++q) {
      if (gt[q] < kk && kk <= ge[q]) {
        packed = ((unsigned)(4 * l + q) << 24) | ((ge[q] - gt[q]) << 12) | (kk - gt[q]);
        found = true;
      }
    }
    unsigned long long bal = __ballot(found);
    int srcl = __ffsll((long long)bal) - 1;
    packed = __shfl(packed, srcl);
    const unsigned cnt = (packed >> 12) & 0xFFFu;
    kk = packed & 0xFFFu;
    prefix |= (packed >> 24) << shift;
    done |= 0xFFu << shift;
    if (cnt == 1u) {
      unsigned cand = 0;
      #pragma unroll
      for (int q = 0; q < 32; ++q) {
        unsigned kj = keys[q];
        bool in = pos ? (kj > KEY_P0) : (kj < KEY_N0);
        if (in && (kj & done) == prefix) cand = kj;
      }
      #pragma unroll
      for (int d = 1; d < 64; d <<= 1) cand |= __shfl_xor(cand, d);
      T = cand;
      resolved = true;
      break;
    }
  }
  if (!resolved) T = prefix;
  T_ret = T;
  kk_ret = kk;
}

__global__ __launch_bounds__(256) void k_final(const float* __restrict__ scores,
                                               const float* __restrict__ randu,
                                               const unsigned* __restrict__ gwords,
                                               float* __restrict__ out) {
  __shared__ __align__(16) unsigned hist[4][256];
  __shared__ unsigned gm[4][64];
  const int l = threadIdx.x & 63;          // lane
  const int w = threadIdx.x >> 6;          // wave in block
  const int row = blockIdx.x * 4 + w;      // (b*8 + h)*2048 + i
  const int i = row & 2047;
  const int b = row >> 14;
  const size_t base = (size_t)row * S_LEN;
  const float thr = (float)(1.0 - 0.8);    // 0x3E4CCCCD, JAX f32 demotion
  unsigned* h = hist[w];
  unsigned* g = gm[w];

  g[l] = gwords[((size_t)(b << 11) + i) * 64 + l];
  // no barrier: wave-private slice, LDS in-order within the wave

  const int bitbase = 4 * (l & 7);
  unsigned keys[32];
  unsigned np = 0, n0 = 0, n1 = 0;         // wave-uniform (ballot-derived)
  #pragma unroll
  for (int s = 0; s < 8; ++s) {
    const int j0 = 256 * s + 4 * l;
    float4 sc = *(const float4*)(scores + base + j0);
    float4 ru = *(const float4*)(randu + base + j0);
    const unsigned gmw = g[8 * s + (l >> 3)];
    const float scv[4] = {sc.x, sc.y, sc.z, sc.w};
    const float ruv[4] = {ru.x, ru.y, ru.z, ru.w};
    #pragma unroll
    for (int e = 0; e < 4; ++e) {
      const unsigned u = __float_as_uint(scv[e]);
      const unsigned m = (unsigned)((int)u >> 31) | 0x80000000u;
      const bool comb = (((gmw >> (bitbase + e)) & 1u) != 0u) | (ruv[e] < thr);
      const unsigned key = (comb ? u : (u & 0x80000000u)) ^ m;
      keys[4 * s + e] = key;
      np += (unsigned)__popcll(__ballot(key > KEY_P0));
      n0 += (unsigned)__popcll(__ballot(key == KEY_P0));
      n1 += (unsigned)__popcll(__ballot(key == KEY_N0));
    }
  }

  // Resolve threshold T and tie-take count kk (wave-uniform branches).
  unsigned T, kk;
  if (TOPK <= np) {
    radix_range(keys, TOPK, true, h, l, T, kk);           // among positives
  } else if (TOPK <= np + n0) {
    T = KEY_P0; kk = TOPK - np;                           // ~50% of rows
  } else if (TOPK <= np + n0 + n1) {
    T = KEY_N0; kk = TOPK - np - n0;
  } else {
    radix_range(keys, TOPK - np - n0 - n1, false, h, l, T, kk);  // negatives
  }

  // Selection: uniform fast paths; fine rank only in the tie-boundary block.
  unsigned S_tot = 0;                        // ties in blocks s' < s (uniform)
  #pragma unroll
  for (int s = 0; s < 8; ++s) {
    unsigned long long beq[4];
    unsigned pe[4];
    #pragma unroll
    for (int e = 0; e < 4; ++e) {
      beq[e] = __ballot(keys[4 * s + e] == T);
      pe[e] = (unsigned)__popcll(beq[e]);
    }
    const unsigned th = pe[0] + pe[1] + pe[2] + pe[3];
    float v[4] __attribute__((aligned(16)));
    if (S_tot + th <= kk) {                  // every tie here selected
      #pragma unroll
      for (int e = 0; e < 4; ++e)
        v[e] = (keys[4 * s + e] >= T) ? 1.0f : 0.0f;
    } else if (S_tot >= kk) {                // no tie here selected
      #pragma unroll
      for (int e = 0; e < 4; ++e)
        v[e] = (keys[4 * s + e] > T) ? 1.0f : 0.0f;
    } else {                                 // boundary block (exactly one)
      unsigned mb[4], own[4];
      #pragma unroll
      for (int e = 0; e < 4; ++e) {
        mb[e]  = mbcnt64(beq[e]);
        own[e] = (unsigned)((beq[e] >> l) & 1ull);
      }
      const unsigned cross = S_tot + mb[0] + mb[1] + mb[2] + mb[3];
      unsigned run = 0;
      #pragma unroll
      for (int e = 0; e < 4; ++e) {
        unsigned kj = keys[4 * s + e];
        bool sel = (kj > T) || (kj == T && (cross + run) < kk);
        run += own[e];
        v[e] = sel ? 1.0f : 0.0f;
      }
    }
    S_tot += th;
    *(float4*)(out + base + 256 * s + 4 * l) = *(const float4*)v;
  }
}

extern "C" void kernel_launch(void* const* d_in, const int* in_sizes, int n_in,
                              void* d_out, int out_size, void* d_ws, size_t ws_size,
                              hipStream_t stream) {
  const float* scores = (const float*)d_in[0];
  const float* randu  = (const float*)d_in[1];
  float* out = (float*)d_out;
  unsigned* gwords = (unsigned*)d_ws;  // needs N_BATCH*S_LEN*256 B = 1 MiB
  k_gmask<<<N_BATCH * S_LEN, NT, 0, stream>>>(scores, gwords);
  k_final<<<N_BATCH * N_HEADS * S_LEN / 4, 256, 0, stream>>>(scores, randu, gwords, out);
}

// Round 9
// 210.159 us; speedup vs baseline: 1.1080x; 1.0681x over previous
//
#include <hip/hip_runtime.h>
#include <cstdint>
#include <cstddef>

#define S_LEN   2048
#define N_HEADS 8
#define N_BATCH 2
#define TOPK    409      // int(2048 * (1.0 - 0.8)) in python double arithmetic
#define HALF_WIN 32
#define KEY_P0  0x80000000u   // mono(+0.0f)
#define KEY_N0  0x7FFFFFFFu   // mono(-0.0f)  (total order: -0 < +0)

__device__ __forceinline__ unsigned mbcnt64(unsigned long long m) {
  return __builtin_amdgcn_mbcnt_hi((unsigned)(m >> 32),
         __builtin_amdgcn_mbcnt_lo((unsigned)m, 0u));
}

// MSD radix select over the positive (key>+0) or negative (key<-0) subset.
// Wave-scope only (no barriers) -> callable by a single wave. cnt1 set when
// resolved with a unique tie (exit-B), enabling the ballot-free select path.
__device__ __forceinline__ void radix_range(const unsigned (&keys)[32], unsigned kk0,
                                            bool pos, unsigned* h, int l,
                                            unsigned& T_ret, unsigned& kk_ret,
                                            bool& cnt1) {
  unsigned prefix = 0, done = 0, kk = kk0;
  unsigned T = 0;
  bool resolved = false;
  cnt1 = false;
  #pragma unroll
  for (int pass = 0; pass < 4; ++pass) {
    const int shift = 24 - 8 * pass;
    *(uint4*)&h[l * 4] = make_uint4(0, 0, 0, 0);
    __threadfence_block();
    #pragma unroll
    for (int q = 0; q < 32; ++q) {
      unsigned kj = keys[q];
      bool in = pos ? (kj > KEY_P0) : (kj < KEY_N0);
      if (in && (kj & done) == prefix)
        atomicAdd(&h[(kj >> shift) & 255u], 1u);
    }
    __threadfence_block();
    uint4 hv = *(const uint4*)&h[l * 4];
    unsigned s3 = hv.w;
    unsigned s2 = hv.z + s3;
    unsigned s1 = hv.y + s2;
    unsigned s0 = hv.x + s1;
    unsigned inc = s0;
    #pragma unroll
    for (int d = 1; d < 64; d <<= 1) {
      unsigned o = __shfl_down(inc, d);
      inc += (l + d < 64) ? o : 0u;
    }
    const unsigned tail = inc - s0;
    const unsigned ge[4] = {s0 + tail, s1 + tail, s2 + tail, s3 + tail};
    const unsigned gt[4] = {s1 + tail, s2 + tail, s3 + tail, tail};
    unsigned packed = 0;
    bool found = false;
    #pragma unroll
    for (int q = 0; q < 4; ++q) {
      if (gt[q] < kk && kk <= ge[q]) {
        packed = ((unsigned)(4 * l + q) << 24) | ((ge[q] - gt[q]) << 12) | (kk - gt[q]);
        found = true;
      }
    }
    unsigned long long bal = __ballot(found);
    int srcl = __ffsll((long long)bal) - 1;
    packed = __shfl(packed, srcl);
    const unsigned cnt = (packed >> 12) & 0xFFFu;
    kk = packed & 0xFFFu;
    prefix |= (packed >> 24) << shift;
    done |= 0xFFu << shift;
    if (cnt == 1u) {
      unsigned cand = 0;
      #pragma unroll
      for (int q = 0; q < 32; ++q) {
        unsigned kj = keys[q];
        bool in = pos ? (kj > KEY_P0) : (kj < KEY_N0);
        if (in && (kj & done) == prefix) cand = kj;
      }
      #pragma unroll
      for (int d = 1; d < 64; d <<= 1) cand |= __shfl_xor(cand, d);
      T = cand;                              // kk == 1 here
      resolved = true;
      cnt1 = true;
      break;
    }
  }
  if (!resolved) T = prefix;
  T_ret = T;
  kk_ret = kk;
}

// Resolve threshold T + tie-take count kk for top-TOPK of the 2048 keys held
// 32/lane. Order: positives > +0 > -0 > negatives; n0/n1 counted lazily.
__device__ __forceinline__ void resolve_T(const unsigned (&keys)[32], unsigned* h,
                                          int l, unsigned& T, unsigned& kk,
                                          bool& cnt1) {
  unsigned np = 0;
  #pragma unroll
  for (int q = 0; q < 32; ++q)
    np += (unsigned)__popcll(__ballot(keys[q] > KEY_P0));
  if (TOPK <= np) {
    radix_range(keys, TOPK, true, h, l, T, kk, cnt1);
  } else {
    unsigned n0 = 0, n1 = 0;
    #pragma unroll
    for (int q = 0; q < 32; ++q) {
      n0 += (unsigned)__popcll(__ballot(keys[q] == KEY_P0));
      n1 += (unsigned)__popcll(__ballot(keys[q] == KEY_N0));
    }
    if (TOPK <= np + n0)           { T = KEY_P0; kk = TOPK - np;      cnt1 = (n0 == 1); }
    else if (TOPK <= np + n0 + n1) { T = KEY_N0; kk = TOPK - np - n0; cnt1 = (n1 == 1); }
    else radix_range(keys, TOPK - np - n0 - n1, false, h, l, T, kk, cnt1);
  }
}

// Per-lane selection bits (bit q=4s+e <-> column j=256s+4l+e). Stable
// lowest-index-first tie handling; ballot-free fast path when cnt1.
__device__ __forceinline__ unsigned select_bits(const unsigned (&keys)[32],
                                                unsigned T, unsigned kk,
                                                bool cnt1, int l) {
  unsigned bits = 0;
  if (cnt1) {
    #pragma unroll
    for (int q = 0; q < 32; ++q)
      bits |= (keys[q] >= T ? 1u : 0u) << q;
    return bits;
  }
  unsigned S_tot = 0;
  #pragma unroll
  for (int s = 0; s < 8; ++s) {
    unsigned long long beq[4];
    unsigned pe[4];
    #pragma unroll
    for (int e = 0; e < 4; ++e) {
      beq[e] = __ballot(keys[4 * s + e] == T);
      pe[e] = (unsigned)__popcll(beq[e]);
    }
    const unsigned th = pe[0] + pe[1] + pe[2] + pe[3];
    if (S_tot + th <= kk) {                  // every tie in this block kept
      #pragma unroll
      for (int e = 0; e < 4; ++e)
        bits |= (keys[4 * s + e] >= T ? 1u : 0u) << (4 * s + e);
    } else if (S_tot >= kk) {                // no tie in this block kept
      #pragma unroll
      for (int e = 0; e < 4; ++e)
        bits |= (keys[4 * s + e] > T ? 1u : 0u) << (4 * s + e);
    } else {                                 // boundary block (exactly one)
      unsigned mb[4], own[4];
      #pragma unroll
      for (int e = 0; e < 4; ++e) {
        mb[e]  = mbcnt64(beq[e]);
        own[e] = (unsigned)((beq[e] >> l) & 1ull);
      }
      const unsigned cross = S_tot + mb[0] + mb[1] + mb[2] + mb[3];
      unsigned run = 0;
      #pragma unroll
      for (int e = 0; e < 4; ++e) {
        unsigned kj = keys[4 * s + e];
        bool sel = (kj > T) || (kj == T && (cross + run) < kk);
        run += own[e];
        bits |= (sel ? 1u : 0u) << (4 * s + e);
      }
    }
    S_tot += th;
  }
  return bits;
}

// Fused kernel: block = (b,i), 8 waves = 8 heads.
// Phase 1: wave h stages score row h into LDS; compresses rand row to 32 bits.
// Phase 2: wave 0 sums heads in order (bit-exact vs reference mean), runs the
//          wave top-k on the sum, ORs local-window bits, emits 512 nibbles.
// Phase 3: every wave builds masked keys and does its own top-k + write.
__global__ __launch_bounds__(512, 4) void k_fused(const float* __restrict__ scores,
                                                  const float* __restrict__ randu,
                                                  float* __restrict__ out) {
  __shared__ __align__(16) float sc_lds[N_HEADS][S_LEN];
  __shared__ __align__(16) unsigned hist[N_HEADS][256];
  __shared__ unsigned char gbytes[512];
  const int l = threadIdx.x & 63;          // lane
  const int w = threadIdx.x >> 6;          // wave = head
  const int bi = blockIdx.x;               // b * S + i
  const int b = bi >> 11;
  const int i = bi & 2047;
  const size_t row = (((size_t)(b * N_HEADS + w)) * S_LEN + i) * S_LEN;
  const float thr = (float)(1.0 - 0.8);    // 0x3E4CCCCD, JAX f32 demotion

  // ---- Phase 1: stage scores, compress rand ----
  unsigned rndbits = 0;
  #pragma unroll
  for (int s = 0; s < 8; ++s) {
    const int j0 = 256 * s + 4 * l;
    float4 sc = *(const float4*)(scores + row + j0);
    float4 ru = *(const float4*)(randu + row + j0);
    *(float4*)&sc_lds[w][j0] = sc;
    rndbits |= (ru.x < thr ? 1u : 0u) << (4 * s + 0);
    rndbits |= (ru.y < thr ? 1u : 0u) << (4 * s + 1);
    rndbits |= (ru.z < thr ? 1u : 0u) << (4 * s + 2);
    rndbits |= (ru.w < thr ? 1u : 0u) << (4 * s + 3);
  }
  __syncthreads();

  // ---- Phase 2: wave 0 computes gmask nibbles ----
  if (w == 0) {
    unsigned gkeys[32];
    #pragma unroll
    for (int s = 0; s < 8; ++s) {
      const int j0 = 256 * s + 4 * l;
      float4 a = *(const float4*)&sc_lds[0][j0];
      #pragma unroll
      for (int hh = 1; hh < N_HEADS; ++hh) {     // sequential head order
        float4 x = *(const float4*)&sc_lds[hh][j0];
        a.x += x.x; a.y += x.y; a.z += x.z; a.w += x.w;
      }
      const float av[4] = {a.x, a.y, a.z, a.w};
      #pragma unroll
      for (int e = 0; e < 4; ++e) {
        unsigned u = __float_as_uint(av[e]);
        gkeys[4 * s + e] = (u & 0x80000000u) ? ~u : (u | 0x80000000u);
      }
    }
    unsigned T, kk; bool cnt1;
    resolve_T(gkeys, hist[0], l, T, kk, cnt1);
    unsigned bits = select_bits(gkeys, T, kk, cnt1, l);
    const int lo = i - HALF_WIN;             // window [i-32, i+32)
    #pragma unroll
    for (int s = 0; s < 8; ++s) {
      const int j0 = 256 * s + 4 * l;
      unsigned nib = (bits >> (4 * s)) & 0xFu;
      #pragma unroll
      for (int e = 0; e < 4; ++e)
        nib |= ((unsigned)(j0 + e - lo) < 64u ? 1u : 0u) << e;
      gbytes[64 * s + l] = (unsigned char)nib;
    }
  }
  __syncthreads();

  // ---- Phase 3: per-head final top-k ----
  unsigned keys[32];
  #pragma unroll
  for (int s = 0; s < 8; ++s) {
    const int j0 = 256 * s + 4 * l;
    float4 sc = *(const float4*)&sc_lds[w][j0];
    const unsigned cn = (unsigned)gbytes[64 * s + l] | ((rndbits >> (4 * s)) & 0xFu);
    const float scv[4] = {sc.x, sc.y, sc.z, sc.w};
    #pragma unroll
    for (int e = 0; e < 4; ++e) {
      const unsigned u = __float_as_uint(scv[e]);
      const unsigned m = (unsigned)((int)u >> 31) | 0x80000000u;
      const bool comb = ((cn >> e) & 1u) != 0u;
      keys[4 * s + e] = (comb ? u : (u & 0x80000000u)) ^ m;
    }
  }
  unsigned T, kk; bool cnt1;
  resolve_T(keys, hist[w], l, T, kk, cnt1);
  unsigned bits = select_bits(keys, T, kk, cnt1, l);
  #pragma unroll
  for (int s = 0; s < 8; ++s) {
    float v[4] __attribute__((aligned(16)));
    #pragma unroll
    for (int e = 0; e < 4; ++e)
      v[e] = ((bits >> (4 * s + e)) & 1u) ? 1.0f : 0.0f;
    *(float4*)(out + row + 256 * s + 4 * l) = *(const float4*)v;
  }
}

extern "C" void kernel_launch(void* const* d_in, const int* in_sizes, int n_in,
                              void* d_out, int out_size, void* d_ws, size_t ws_size,
                              hipStream_t stream) {
  const float* scores = (const float*)d_in[0];
  const float* randu  = (const float*)d_in[1];
  float* out = (float*)d_out;
  (void)d_ws; (void)ws_size;
  k_fused<<<N_BATCH * S_LEN, 512, 0, stream>>>(scores, randu, out);
}